// Round 1
// 55.561 us; speedup vs baseline: 1.0067x; 1.0067x over previous
//
#include <hip/hip_runtime.h>

// DIM_backprop: depth (B,H,W) fp32 -> BEV soft histogram (B,W,D) fp32.
// sigma=0.5, bin=20 => Gaussian underflows fp32 beyond the nearest bin:
// exactly one bin per valid pixel is nonzero -> scatter into an LDS
// histogram, never densely evaluate (B,H,W,D).
//
// R2 (this round): hide global-load latency. Depth tile is prefetched into
// registers as one float4 per row (w0 multiple of 4 -> 16B aligned) BEFORE
// the LDS zeroing pass, so HBM/L2 latency overlaps the zero + barrier.
// Zero/writeback loops fully unrolled (NV4=401 -> i=tid and i=tid+256).

#define BB 16
#define HH 120
#define WW 160
#define DD 401
#define WT 4                    // columns per block
#define NCOL (WT * DD)          // 1604 floats per block
#define NV4 (NCOL / 4)          // 401 float4s

#define DEPTH_MAX 8000.0f
#define INV_BIN 0.05f           // 1/20
#define SIG_EPS 0.50000001f     // sigma + 1e-8
#define ZERO_EPS 1e-6f
#define GNORM (1.0f / (SIG_EPS * 2.50662827463100050242f))

__global__ __launch_bounds__(256)
void dim_bev_kernel(const float* __restrict__ depth, float* __restrict__ out) {
    __shared__ __align__(16) float hist[NCOL];   // [wi][bin] flat
    const int bi = blockIdx.x;                   // b*40 + wtile
    const int b  = bi / 40;
    const int w0 = (bi - b * 40) * WT;
    const int tid = threadIdx.x;

    // 1) issue depth loads FIRST: thread t<120 prefetches row t's float4.
    //    (depth + b*H*W + w0) is 16B aligned: w0 % 4 == 0.
    const float4* dbase4 = (const float4*)(depth + (size_t)b * HH * WW + w0);
    float4 dv;
    if (tid < HH) dv = dbase4[tid * (WW / 4)];

    // 2) zero LDS histogram under the load latency (fully unrolled:
    //    tid covers [0,256), tid+256 covers [256,401) for tid<145)
    const float4 z4 = make_float4(0.f, 0.f, 0.f, 0.f);
    float4* h4 = (float4*)hist;
    h4[tid] = z4;
    if (tid + 256 < NV4) h4[tid + 256] = z4;
    __syncthreads();

    // 3) scatter: each loading thread handles its row's 4 columns
    if (tid < HH) {
        const float dcol[4] = {dv.x, dv.y, dv.z, dv.w};
        #pragma unroll
        for (int wi = 0; wi < WT; ++wi) {
            const float d = dcol[wi];
            if (isfinite(d) && (d <= DEPTH_MAX) && (d > ZERO_EPS)) {
                int bin = __float2int_rn(d * INV_BIN);
                bin = bin < 0 ? 0 : (bin > DD - 1 ? DD - 1 : bin);
                const float x = (float)bin * 20.0f - d;
                const float zz = x * (1.0f / SIG_EPS);
                const float g = __expf(-0.5f * zz * zz) * GNORM;
                if (g > 0.0f) atomicAdd(&hist[wi * DD + bin], g);
            }
        }
    }
    __syncthreads();

    // 4) vectorized contiguous writeback: hist flat == out[(b,w0..w0+3,:)]
    float4* o4 = (float4*)(out + ((size_t)b * WW + w0) * DD);
    o4[tid] = h4[tid];
    if (tid + 256 < NV4) o4[tid + 256] = h4[tid + 256];
}

extern "C" void kernel_launch(void* const* d_in, const int* in_sizes, int n_in,
                              void* d_out, int out_size, void* d_ws, size_t ws_size,
                              hipStream_t stream) {
    const float* depth = (const float*)d_in[0];
    float* out = (float*)d_out;
    dim_bev_kernel<<<BB * (WW / WT), 256, 0, stream>>>(depth, out);
}